// Round 1
// baseline (547.758 us; speedup 1.0000x reference)
//
#include <hip/hip_runtime.h>
#include <math.h>

#define HEADS 16
#define HEAD_DIM 64
#define HIDDEN 1024
#define NQKVFF 7168
#define VFF 5120
#define SEQ 2048
#define MROWS 4096

typedef unsigned short u16;
typedef __attribute__((ext_vector_type(8))) short bf16x8;
typedef __attribute__((ext_vector_type(4))) float f32x4;
typedef __attribute__((address_space(1))) void gas_void;
typedef __attribute__((address_space(3))) void las_void;

__device__ inline u16 f2bf(float f) {
    union { float f; unsigned u; } v; v.f = f;
    unsigned r = v.u + 0x7FFFu + ((v.u >> 16) & 1u);
    return (u16)(r >> 16);
}
__device__ inline float bf2f(u16 h) {
    union { unsigned u; float f; } v; v.u = ((unsigned)h) << 16;
    return v.f;
}

// ---------------- LayerNorm: fp32 [4096][1024] -> bf16 [4096][1024] ----------
__global__ __launch_bounds__(256) void ln_kernel(const float* __restrict__ x,
        const float* __restrict__ w, const float* __restrict__ b,
        u16* __restrict__ xn) {
    int row = blockIdx.x;
    int tid = threadIdx.x;
    const float* xr = x + (size_t)row * HIDDEN;
    float4 v = ((const float4*)xr)[tid];
    float s = v.x + v.y + v.z + v.w;
    float sq = v.x * v.x + v.y * v.y + v.z * v.z + v.w * v.w;
    for (int off = 32; off > 0; off >>= 1) {
        s += __shfl_down(s, off, 64);
        sq += __shfl_down(sq, off, 64);
    }
    __shared__ float ls[4], lsq[4];
    int wid = tid >> 6, lane = tid & 63;
    if (lane == 0) { ls[wid] = s; lsq[wid] = sq; }
    __syncthreads();
    float ts = ls[0] + ls[1] + ls[2] + ls[3];
    float tsq = lsq[0] + lsq[1] + lsq[2] + lsq[3];
    float mu = ts * (1.0f / HIDDEN);
    float var = tsq * (1.0f / HIDDEN) - mu * mu;
    float rstd = rsqrtf(var + 1e-5f);
    float4 wv = ((const float4*)w)[tid];
    float4 bv = ((const float4*)b)[tid];
    ushort4 o;
    o.x = f2bf((v.x - mu) * rstd * wv.x + bv.x);
    o.y = f2bf((v.y - mu) * rstd * wv.y + bv.y);
    o.z = f2bf((v.z - mu) * rstd * wv.z + bv.z);
    o.w = f2bf((v.w - mu) * rstd * wv.w + bv.w);
    ((ushort4*)(xn + (size_t)row * HIDDEN))[tid] = o;
}

// ---------- Transpose + cast: fp32 in[R][C] -> bf16 out[C][R] ----------------
__global__ __launch_bounds__(256) void transpose_f2b(const float* __restrict__ in,
        u16* __restrict__ out, int R, int C) {
    __shared__ u16 tile[32][33];
    int c0 = blockIdx.x * 32, r0 = blockIdx.y * 32;
    int tx = threadIdx.x & 31, ty = threadIdx.x >> 5;
#pragma unroll
    for (int k = 0; k < 4; k++)
        tile[ty + k * 8][tx] = f2bf(in[(size_t)(r0 + ty + k * 8) * C + c0 + tx]);
    __syncthreads();
#pragma unroll
    for (int k = 0; k < 4; k++)
        out[(size_t)(c0 + ty + k * 8) * R + r0 + tx] = tile[tx][ty + k * 8];
}

// ---------- Transpose V: bf16 [32][2048][64] -> [32][64][2048] ---------------
__global__ __launch_bounds__(256) void transpose_v(const u16* __restrict__ in,
        u16* __restrict__ out) {
    __shared__ u16 tile[32][33];
    int bh = blockIdx.x, it = blockIdx.y, dt = blockIdx.z;
    const u16* src = in + (size_t)bh * SEQ * HEAD_DIM;
    u16* dst = out + (size_t)bh * HEAD_DIM * SEQ;
    int tx = threadIdx.x & 31, ty = threadIdx.x >> 5;
    int i0 = it * 32, d0 = dt * 32;
#pragma unroll
    for (int k = 0; k < 4; k++)
        tile[ty + k * 8][tx] = src[(size_t)(i0 + ty + k * 8) * HEAD_DIM + d0 + tx];
    __syncthreads();
#pragma unroll
    for (int k = 0; k < 4; k++)
        dst[(size_t)(d0 + ty + k * 8) * SEQ + i0 + tx] = tile[tx][ty + k * 8];
}

// ---------------- RoPE in-place on q,k: [2][32][2048][64] bf16 ---------------
__global__ __launch_bounds__(256) void rope_kernel(u16* __restrict__ qk) {
    int idx = blockIdx.x * 256 + threadIdx.x;   // 2*32*2048*32 total
    int j = idx & 31;
    int i = (idx >> 5) & 2047;
    int rest = idx >> 16;                       // t*32 + bh, 0..63
    u16* base = qk + ((size_t)rest * SEQ + i) * HEAD_DIM;
    float x1 = bf2f(base[j]), x2 = bf2f(base[j + 32]);
    float f = expf(j * -0.28782313662425572f);  // 10000^(-j/32)
    float ang = i * f;
    float s, c;
    sincosf(ang, &s, &c);
    base[j] = f2bf(x1 * c - x2 * s);
    base[j + 32] = f2bf(x2 * c + x1 * s);
}

// ---------------- 128x128x32 bf16 MFMA GEMM core (m97 structure) -------------
// A[M][K] bf16 row-major; BT[N][K] bf16 (i.e. B transposed). 256 threads.
__device__ inline void gemm_core_128(const u16* __restrict__ A, const u16* __restrict__ BT,
                                     int K, int bm, int bn, f32x4 acc[4][4],
                                     u16* ldsA, u16* ldsB) {
    const int tid = threadIdx.x;
    const int wid = tid >> 6;
    const int lane = tid & 63;
    const int quad = lane >> 4;
    const int cc = lane & 15;
    const int wm = (wid >> 1) * 64;
    const int wn = (wid & 1) * 64;
#pragma unroll
    for (int i = 0; i < 4; i++)
#pragma unroll
        for (int j = 0; j < 4; j++)
#pragma unroll
            for (int r = 0; r < 4; r++) acc[i][j][r] = 0.0f;

    const int row = tid >> 2;    // 0..63
    const int chunk = tid & 3;
    for (int k0 = 0; k0 < K; k0 += 32) {
        __syncthreads();
#pragma unroll
        for (int I = 0; I < 2; I++) {
            int r128 = I * 64 + row;
            const u16* ga = A + (size_t)(bm + r128) * K + k0 + chunk * 8;
            u16* la = ldsA + ((size_t)(I * 256 + (tid & 192))) * 8;
            __builtin_amdgcn_global_load_lds((gas_void*)ga, (las_void*)la, 16, 0, 0);
            const u16* gb = BT + (size_t)(bn + r128) * K + k0 + chunk * 8;
            u16* lb = ldsB + ((size_t)(I * 256 + (tid & 192))) * 8;
            __builtin_amdgcn_global_load_lds((gas_void*)gb, (las_void*)lb, 16, 0, 0);
        }
        __syncthreads();
        bf16x8 af[4], bfr[4];
#pragma unroll
        for (int t = 0; t < 4; t++) {
            af[t]  = *(const bf16x8*)(ldsA + (wm + t * 16 + cc) * 32 + quad * 8);
            bfr[t] = *(const bf16x8*)(ldsB + (wn + t * 16 + cc) * 32 + quad * 8);
        }
#pragma unroll
        for (int i = 0; i < 4; i++)
#pragma unroll
            for (int j = 0; j < 4; j++)
                acc[i][j] = __builtin_amdgcn_mfma_f32_16x16x32_bf16(af[i], bfr[j], acc[i][j], 0, 0, 0);
    }
}

// GEMM1: xn[4096][1024] @ W_in -> scatter q,k,v into qkv[3][32][2048][64],
// gelu(ff) into a2[:, 1024:5120]
__global__ __launch_bounds__(256) void gemm1(const u16* __restrict__ xn,
        const u16* __restrict__ WinT, u16* __restrict__ qkv, u16* __restrict__ a2) {
    __shared__ u16 ldsA[128 * 32];
    __shared__ u16 ldsB[128 * 32];
    int bm = blockIdx.x * 128, bn = blockIdx.y * 128;
    f32x4 acc[4][4];
    gemm_core_128(xn, WinT, HIDDEN, bm, bn, acc, ldsA, ldsB);
    const int tid = threadIdx.x, wid = tid >> 6, lane = tid & 63;
    const int quad = lane >> 4, cc = lane & 15;
    const int wm = (wid >> 1) * 64, wn = (wid & 1) * 64;
    const bool isff = (bn >= 3072);
#pragma unroll
    for (int i = 0; i < 4; i++)
#pragma unroll
        for (int j = 0; j < 4; j++)
#pragma unroll
            for (int r = 0; r < 4; r++) {
                int m = bm + wm + i * 16 + quad * 4 + r;
                int n = bn + wn + j * 16 + cc;
                float v = acc[i][j][r];
                if (isff) {
                    float g = 0.5f * v * (1.0f + erff(v * 0.70710678118654752f));
                    a2[(size_t)m * VFF + (n - 2048)] = f2bf(g);   // cols 1024..5119
                } else {
                    int t = n >> 10;          // 0=q 1=k 2=v
                    int hh = (n >> 6) & 15;
                    int d = n & 63;
                    int bb = m >> 11, ii = m & 2047;
                    qkv[(((size_t)t * 32 + bb * 16 + hh) * SEQ + ii) * HEAD_DIM + d] = f2bf(v);
                }
            }
}

// GEMM2: a2[4096][5120] @ W_out -> out fp32 [4096][1024]
__global__ __launch_bounds__(256) void gemm2(const u16* __restrict__ a2,
        const u16* __restrict__ WoutT, float* __restrict__ out) {
    __shared__ u16 ldsA[128 * 32];
    __shared__ u16 ldsB[128 * 32];
    int bm = blockIdx.x * 128, bn = blockIdx.y * 128;
    f32x4 acc[4][4];
    gemm_core_128(a2, WoutT, VFF, bm, bn, acc, ldsA, ldsB);
    const int tid = threadIdx.x, wid = tid >> 6, lane = tid & 63;
    const int quad = lane >> 4, cc = lane & 15;
    const int wm = (wid >> 1) * 64, wn = (wid & 1) * 64;
#pragma unroll
    for (int i = 0; i < 4; i++)
#pragma unroll
        for (int j = 0; j < 4; j++)
#pragma unroll
            for (int r = 0; r < 4; r++) {
                int m = bm + wm + i * 16 + quad * 4 + r;
                int n = bn + wn + j * 16 + cc;
                out[(size_t)m * HIDDEN + n] = acc[i][j][r];
            }
}

// ---------------- Flash attention, causal, MFMA ------------------------------
// grid (32 qtiles, 32 bh). Each wave: 16 q rows. Key tiles of 32.
__global__ __launch_bounds__(256) void attn_kernel(const u16* __restrict__ qkv,
        const u16* __restrict__ vt, u16* __restrict__ a2) {
    const int qt = blockIdx.x;
    const int bh = blockIdx.y;
    const int tid = threadIdx.x;
    const int wid = tid >> 6;
    const int lane = tid & 63;
    const int quad = lane >> 4;
    const int cc = lane & 15;

    const u16* Q  = qkv + (size_t)bh * SEQ * HEAD_DIM;
    const u16* Kp = qkv + (size_t)(32 + bh) * SEQ * HEAD_DIM;
    const u16* VT = vt + (size_t)bh * HEAD_DIM * SEQ;

    const int q0 = qt * 64 + wid * 16;
    // Q fragments (A-operand layout): Q[q0+cc][quad*8+j], d-halves 0..31 / 32..63
    bf16x8 qa0 = *(const bf16x8*)(Q + (size_t)(q0 + cc) * HEAD_DIM + quad * 8);
    bf16x8 qa1 = *(const bf16x8*)(Q + (size_t)(q0 + cc) * HEAD_DIM + 32 + quad * 8);

    float mrow[4], lrow[4];
    f32x4 ot[4];   // O^T accum: ot[mt][r] = O^T[mt*16+quad*4+r][cc]
#pragma unroll
    for (int r = 0; r < 4; r++) { mrow[r] = -1e30f; lrow[r] = 0.0f; }
#pragma unroll
    for (int t = 0; t < 4; t++)
#pragma unroll
        for (int r = 0; r < 4; r++) ot[t][r] = 0.0f;

    __shared__ u16 pls[4][2 * 512];     // per-wave P double buffer (16x32 bf16)
    __shared__ float sstat[4][16];      // per-wave per-q-row broadcast
    __shared__ u16 ols[4][16 * 64];     // per-wave O staging for coalesced store

    const int ktmax = (q0 + 15) >> 5;
    for (int kt = 0; kt <= ktmax; kt++) {
        const int kb = kt * 32;
        // S = Q K^T for 32 keys (two 16-key C tiles)
        bf16x8 k0a = *(const bf16x8*)(Kp + (size_t)(kb + cc) * HEAD_DIM + quad * 8);
        bf16x8 k0b = *(const bf16x8*)(Kp + (size_t)(kb + cc) * HEAD_DIM + 32 + quad * 8);
        bf16x8 k1a = *(const bf16x8*)(Kp + (size_t)(kb + 16 + cc) * HEAD_DIM + quad * 8);
        bf16x8 k1b = *(const bf16x8*)(Kp + (size_t)(kb + 16 + cc) * HEAD_DIM + 32 + quad * 8);
        f32x4 s0, s1;
#pragma unroll
        for (int r = 0; r < 4; r++) { s0[r] = 0.0f; s1[r] = 0.0f; }
        s0 = __builtin_amdgcn_mfma_f32_16x16x32_bf16(qa0, k0a, s0, 0, 0, 0);
        s0 = __builtin_amdgcn_mfma_f32_16x16x32_bf16(qa1, k0b, s0, 0, 0, 0);
        s1 = __builtin_amdgcn_mfma_f32_16x16x32_bf16(qa0, k1a, s1, 0, 0, 0);
        s1 = __builtin_amdgcn_mfma_f32_16x16x32_bf16(qa1, k1b, s1, 0, 0, 0);

        float t0[4], t1[4], alpha[4];
#pragma unroll
        for (int r = 0; r < 4; r++) {
            int qrow = q0 + quad * 4 + r;
            t0[r] = (kb + cc <= qrow) ? s0[r] * 0.125f : -1e30f;
            t1[r] = (kb + 16 + cc <= qrow) ? s1[r] * 0.125f : -1e30f;
        }
#pragma unroll
        for (int r = 0; r < 4; r++) {
            float mx = fmaxf(t0[r], t1[r]);
#pragma unroll
            for (int o = 1; o < 16; o <<= 1) mx = fmaxf(mx, __shfl_xor(mx, o, 64));
            float mnew = fmaxf(mrow[r], mx);
            float p0 = __expf(t0[r] - mnew);
            float p1 = __expf(t1[r] - mnew);
            t0[r] = p0; t1[r] = p1;
            float ps = p0 + p1;
#pragma unroll
            for (int o = 1; o < 16; o <<= 1) ps += __shfl_xor(ps, o, 64);
            alpha[r] = __expf(mrow[r] - mnew);
            lrow[r] = lrow[r] * alpha[r] + ps;
            mrow[r] = mnew;
        }
        // broadcast alpha per q-row through LDS; stage P (bf16) for layout swap
        if (cc == 0) {
#pragma unroll
            for (int r = 0; r < 4; r++) sstat[wid][quad * 4 + r] = alpha[r];
        }
        u16* P = pls[wid] + (kt & 1) * 512;
#pragma unroll
        for (int r = 0; r < 4; r++) {
            P[(quad * 4 + r) * 32 + cc] = f2bf(t0[r]);
            P[(quad * 4 + r) * 32 + 16 + cc] = f2bf(t1[r]);
        }
        asm volatile("s_waitcnt lgkmcnt(0)" ::: "memory");
        float aq = sstat[wid][cc];
#pragma unroll
        for (int t = 0; t < 4; t++)
#pragma unroll
            for (int r = 0; r < 4; r++) ot[t][r] *= aq;
        // B-operand read of P^T: P[cc][quad*8+j]
        bf16x8 pb = *(const bf16x8*)(P + cc * 32 + quad * 8);
        // O^T += V^T P^T
#pragma unroll
        for (int mt = 0; mt < 4; mt++) {
            bf16x8 va = *(const bf16x8*)(VT + (size_t)(mt * 16 + cc) * SEQ + kb + quad * 8);
            ot[mt] = __builtin_amdgcn_mfma_f32_16x16x32_bf16(va, pb, ot[mt], 0, 0, 0);
        }
        asm volatile("s_waitcnt lgkmcnt(0)" ::: "memory");
    }

    // normalize by l and store (via LDS transpose for coalesced writes)
    if (cc == 0) {
#pragma unroll
        for (int r = 0; r < 4; r++) sstat[wid][quad * 4 + r] = 1.0f / lrow[r];
    }
    asm volatile("s_waitcnt lgkmcnt(0)" ::: "memory");
    float rl = sstat[wid][cc];
    u16* O = ols[wid];
#pragma unroll
    for (int mt = 0; mt < 4; mt++)
#pragma unroll
        for (int r = 0; r < 4; r++)
            O[cc * 64 + mt * 16 + quad * 4 + r] = f2bf(ot[mt][r] * rl);
    asm volatile("s_waitcnt lgkmcnt(0)" ::: "memory");
    {
        int qr = lane >> 2, ch = lane & 3;
        int bb = bh >> 4, hh = bh & 15;
        int i = q0 + qr;
        u16* dst = a2 + ((size_t)(bb * SEQ + i)) * VFF + hh * 64 + ch * 16;
        *(bf16x8*)dst = *(const bf16x8*)(O + qr * 64 + ch * 16);
        *(bf16x8*)(dst + 8) = *(const bf16x8*)(O + qr * 64 + ch * 16 + 8);
    }
}

extern "C" void kernel_launch(void* const* d_in, const int* in_sizes, int n_in,
                              void* d_out, int out_size, void* d_ws, size_t ws_size,
                              hipStream_t stream) {
    const float* x     = (const float*)d_in[0];
    const float* ln_w  = (const float*)d_in[1];
    const float* ln_b  = (const float*)d_in[2];
    const float* W_in  = (const float*)d_in[3];
    const float* W_out = (const float*)d_in[4];
    float* out = (float*)d_out;
    char* ws = (char*)d_ws;
    // workspace layout (bytes)
    u16* xn    = (u16*)(ws);                       //  8 MB  [4096][1024]
    u16* WinT  = (u16*)(ws + 8388608);             // 14 MB  [7168][1024]
    u16* WoutT = (u16*)(ws + 23068672);            // 10 MB  [1024][5120]
    u16* qkv   = (u16*)(ws + 33554432);            // 24 MB  [3][32][2048][64]
    u16* vtb   = (u16*)(ws + 58720256);            //  8 MB  [32][64][2048]
    u16* a2    = (u16*)(ws + 67108864);            // 40 MB  [4096][5120]

    ln_kernel<<<dim3(MROWS), dim3(256), 0, stream>>>(x, ln_w, ln_b, xn);
    transpose_f2b<<<dim3(NQKVFF / 32, HIDDEN / 32), dim3(256), 0, stream>>>(W_in, WinT, HIDDEN, NQKVFF);
    transpose_f2b<<<dim3(HIDDEN / 32, VFF / 32), dim3(256), 0, stream>>>(W_out, WoutT, VFF, HIDDEN);
    gemm1<<<dim3(MROWS / 128, NQKVFF / 128), dim3(256), 0, stream>>>(xn, WinT, qkv, a2);
    rope_kernel<<<dim3(16384), dim3(256), 0, stream>>>(qkv);
    transpose_v<<<dim3(32, SEQ / 32, HEAD_DIM / 32), dim3(256), 0, stream>>>(
        qkv + (size_t)2 * 32 * SEQ * HEAD_DIM, vtb);
    attn_kernel<<<dim3(SEQ / 64, 32), dim3(256), 0, stream>>>(qkv, vtb, a2);
    gemm2<<<dim3(MROWS / 128, HIDDEN / 128), dim3(256), 0, stream>>>(a2, WoutT, out);
}